// Round 1
// 843.549 us; speedup vs baseline: 1.0334x; 1.0334x over previous
//
#include <hip/hip_runtime.h>
#include <hip/hip_bf16.h>
#include <math.h>

#define B_  32
#define S_  2048
#define H_  1024
#define M_TOT (B_ * S_)   // 65536 rows

typedef __bf16 bf16x8 __attribute__((ext_vector_type(8)));
typedef float  f32x4  __attribute__((ext_vector_type(4)));

// f32 -> bf16 round-to-nearest-even
__device__ __forceinline__ unsigned short f2bf(float f) {
    union { float f; unsigned int u; } v; v.f = f;
    unsigned int u = v.u;
    return (unsigned short)((u + 0x7fffu + ((u >> 16) & 1u)) >> 16);
}

__device__ __forceinline__ float bf2f(unsigned short s) {
    return __uint_as_float(((unsigned int)s) << 16);
}

// tanh via exp2-based expf: ~6 VALU insts, saturates correctly for |x| large
__device__ __forceinline__ float fast_tanh(float x) {
    float e = __expf(2.0f * x);
    return 1.0f - 2.0f / (e + 1.0f);
}

// ---------------------------------------------------------------------------
// Kernel 1: mean over s + f32->bf16 convert. grid (32 b, 64 sc of 32 rows).
// ---------------------------------------------------------------------------
__global__ void k_meanconv(const float* __restrict__ x,
                           unsigned short* __restrict__ xbf,
                           float* __restrict__ meanOut /* pre-zeroed */) {
    int b  = blockIdx.x;
    int sc = blockIdx.y;
    int t  = threadIdx.x;
    size_t base = ((size_t)b * S_ + (size_t)sc * 32) * H_;
    const float4* xr = (const float4*)(x + base);
    ushort4* xo = (ushort4*)(xbf + base);
    float a0 = 0.f, a1 = 0.f, a2 = 0.f, a3 = 0.f;
    for (int s = 0; s < 32; ++s) {
        float4 v = xr[(size_t)s * 256 + t];
        a0 += v.x; a1 += v.y; a2 += v.z; a3 += v.w;
        ushort4 o;
        o.x = f2bf(v.x); o.y = f2bf(v.y); o.z = f2bf(v.z); o.w = f2bf(v.w);
        xo[(size_t)s * 256 + t] = o;
    }
    const float scl = 1.0f / (float)S_;
    float* mp = meanOut + b * H_ + t * 4;
    atomicAdd(mp + 0, a0 * scl);
    atomicAdd(mp + 1, a1 * scl);
    atomicAdd(mp + 2, a2 * scl);
    atomicAdd(mp + 3, a3 * scl);
}

// ---------------------------------------------------------------------------
// Kernel 2: W1|W2 -> bf16 transposed  WT[n][k] = W(hop)[k][n]
// ---------------------------------------------------------------------------
__global__ void k_wconv(const float* __restrict__ W1,
                        const float* __restrict__ W2,
                        unsigned short* __restrict__ WT) {
    int n = blockIdx.x;
    int t = threadIdx.x;
    const float* src = (n < H_) ? (W1 + n) : (W2 + (n - H_));
    unsigned short* dst = WT + (size_t)n * H_;
    for (int kk = 0; kk < 4; ++kk) {
        int k = t + kk * 256;
        dst[k] = f2bf(src[(size_t)k * H_]);
    }
}

// ---------------------------------------------------------------------------
// Kernel 3a: partial (m_hop[b] @ Wm) over an H-chunk -> atomicAdd into vtmp
// ---------------------------------------------------------------------------
__global__ void k_vpart(const float* __restrict__ meanIn,
                        const float* __restrict__ q,
                        const float* __restrict__ Wm1,
                        const float* __restrict__ Wm2,
                        float* __restrict__ vtmp /* pre-zeroed */) {
    int b   = blockIdx.x;
    int hop = blockIdx.y;
    int hc  = blockIdx.z;
    int t   = threadIdx.x;
    __shared__ float mL[128];
    float scale = (hop == 0) ? 1.0f : 2.0f;
    int h0 = hc * 128;
    if (t < 128)
        mL[t] = meanIn[b * H_ + h0 + t] * q[b * H_ + h0 + t] * scale;
    __syncthreads();
    const float* Wm = hop ? Wm2 : Wm1;
    int d0 = t * 4;
    float a0 = 0.f, a1 = 0.f, a2 = 0.f, a3 = 0.f;
    for (int h = 0; h < 128; ++h) {
        float m = mL[h];
        float4 w = *(const float4*)(Wm + (size_t)(h0 + h) * H_ + d0);
        a0 += m * w.x; a1 += m * w.y; a2 += m * w.z; a3 += m * w.w;
    }
    float* vo = vtmp + b * 2048 + hop * H_ + d0;
    atomicAdd(vo + 0, a0);
    atomicAdd(vo + 1, a1);
    atomicAdd(vo + 2, a2);
    atomicAdd(vo + 3, a3);
}

// Kernel 3b: vcat = tanh(vtmp) * Wh.  grid 256, block 256.
__global__ void k_vfin(const float* __restrict__ vtmp,
                       const float* __restrict__ Wh1,
                       const float* __restrict__ Wh2,
                       float* __restrict__ vcat) {
    int i = blockIdx.x * 256 + threadIdx.x;   // [0, 65536)
    int hop = (i >> 10) & 1;
    int d = i & 1023;
    const float* Wh = hop ? Wh2 : Wh1;
    vcat[i] = tanhf(vtmp[i]) * Wh[d];
}

// ---------------------------------------------------------------------------
// Kernel 4: fused GEMM  P = Xbf @ WT^T (M=65536, N=2048, K=1024), bf16 MFMA
//   epilogue: U[hop][row] += sum_n fast_tanh(P[row,n]) * vcat[b,n]
//
// 256x256 tile, BK=64, 8 waves (2Mx4N), 128 KiB double-buffered LDS.
// 8-phase-style schedule (T3+T4+T5+T1):
//   per K-tile v, 4 quadrant phases (QM,QN) = (0,0),(0,1),(1,0),(1,1):
//     { ds_read subtile ; stage part of tile v+2 ; barrier ; lgkmcnt(0) ;
//       setprio(1) ; 16 MFMA ; setprio(0) ; barrier }
//   Each LDS region is read exactly once per tile (frags persist in regs):
//     A-QM0@ph1, B-QN0@ph1, B-QN1@ph2, A-QM1@ph3  -> tile v+2 can stage into
//   the *current* buffer regions one barrier after their last read:
//     ph2: A(v+2) rows 0-63,128-191 | ph3: B(v+2) rows 0-127
//     ph4: B(v+2) rows 128-255 + A(v+2) rows 64-127,192-255
//   => every load has a full tile of compute in flight before its guard:
//   vmcnt(8) once per tile at the ph4 end barrier (never 0 in steady state).
// LDS swizzle: chunk slot = (c + row) & 7 within each 128-B row (2-way = free
// on ds_read_b128); applied via inverse-swizzled GLOBAL source addresses so
// global_load_lds destinations stay linear.
// XCD swizzle: 2048 wgs, chunk-per-XCD, nt-inner => B (4 MB) L2-resident.
// ---------------------------------------------------------------------------
__global__ __launch_bounds__(512, 2) void k_gemm(const unsigned short* __restrict__ Xbf,
                                                 const unsigned short* __restrict__ WT,
                                                 const float* __restrict__ vcat,
                                                 float* __restrict__ U /* pre-zeroed */) {
    int raw = blockIdx.x;                 // 0..2047
    int wg  = (raw & 7) * 256 + (raw >> 3);   // bijective XCD swizzle (2048 % 8 == 0)
    int nt = wg & 7;                      // 0..7
    int mt = wg >> 3;                     // 0..255
    int m0 = mt * 256;
    int n0 = nt * 256;

    int t    = threadIdx.x;               // 0..511
    int lane = t & 63;
    int wave = t >> 6;                    // 0..7
    int wm = wave >> 2;                   // 0..1  (M half)
    int wn = wave & 3;                    // 0..3  (N quarter)
    int fr = lane & 15;
    int fq = lane >> 4;
    int s0 = (fq + fr) & 7;               // swizzled chunk slot for kk=0

    __shared__ unsigned short lds[2][2][256 * 64];   // [buf][A|B], 128 KiB total

    // ---- staging addresses: load L covers lds idx = L*512 + t (linear dest)
    const unsigned short* gA[4];
    const unsigned short* gB[4];
#pragma unroll
    for (int L = 0; L < 4; ++L) {
        int idx  = L * 512 + t;
        int row  = idx >> 3;
        int cst  = idx & 7;
        int csrc = (cst - row) & 7;       // inverse swizzle on the global side
        gA[L] = Xbf + (size_t)(m0 + row) * H_ + csrc * 8;
        gB[L] = WT  + (size_t)(n0 + row) * H_ + csrc * 8;
    }

#define STG_A(buf_, L_, v_) __builtin_amdgcn_global_load_lds( \
        (const __attribute__((address_space(1))) void*)(gA[L_] + (v_) * 64), \
        (__attribute__((address_space(3))) void*)(&lds[buf_][0][(L_) * 4096 + t * 8]), 16, 0, 0)
#define STG_B(buf_, L_, v_) __builtin_amdgcn_global_load_lds( \
        (const __attribute__((address_space(1))) void*)(gB[L_] + (v_) * 64), \
        (__attribute__((address_space(3))) void*)(&lds[buf_][1][(L_) * 4096 + t * 8]), 16, 0, 0)

    // ---- fragment reads (swizzled): row*128B + slot*16B, slot = s0 ^ (4*kk)
#define ARD(buf_, QM_, i_, kk_) \
    (*(const bf16x8*)&lds[buf_][0][(wm * 128 + (QM_) * 64 + (i_) * 16 + fr) * 64 + (s0 ^ ((kk_) * 4)) * 8])
#define BRD(buf_, QN_, j_, kk_) \
    (*(const bf16x8*)&lds[buf_][1][(wn * 64 + (QN_) * 32 + (j_) * 16 + fr) * 64 + (s0 ^ ((kk_) * 4)) * 8])

    // epilogue weights, loaded early (completes long before first vmcnt guard)
    int b   = m0 >> 11;
    int hop = n0 >> 10;
    float vv[4];
#pragma unroll
    for (int j = 0; j < 4; ++j)
        vv[j] = vcat[b * 2048 + n0 + wn * 64 + j * 16 + fr];

    f32x4 acc[8][4];
#pragma unroll
    for (int i = 0; i < 8; ++i)
#pragma unroll
        for (int j = 0; j < 4; ++j)
#pragma unroll
            for (int r = 0; r < 4; ++r) acc[i][j][r] = 0.0f;

    // ---- prologue: stage tiles 0 and 1 fully; allow tile 1 (8 loads) in flight
    STG_A(0, 0, 0); STG_A(0, 1, 0); STG_A(0, 2, 0); STG_A(0, 3, 0);
    STG_B(0, 0, 0); STG_B(0, 1, 0); STG_B(0, 2, 0); STG_B(0, 3, 0);
    STG_A(1, 0, 1); STG_A(1, 1, 1); STG_A(1, 2, 1); STG_A(1, 3, 1);
    STG_B(1, 0, 1); STG_B(1, 1, 1); STG_B(1, 2, 1); STG_B(1, 3, 1);
    asm volatile("s_waitcnt vmcnt(8)" ::: "memory");
    __builtin_amdgcn_s_barrier();
    __builtin_amdgcn_sched_barrier(0);

    bf16x8 a[4][2];
    bf16x8 b0[2][2], b1[2][2];

#pragma unroll 2
    for (int v = 0; v < 16; ++v) {
        int cur = v & 1;
        bool sN2 = (v <= 13);             // stage tile v+2 into buf cur

        // ======== phase 1: quadrant (0,0); reads A-QM0 (8) + B-QN0 (4) ========
#pragma unroll
        for (int i = 0; i < 4; ++i) { a[i][0] = ARD(cur, 0, i, 0); a[i][1] = ARD(cur, 0, i, 1); }
#pragma unroll
        for (int j = 0; j < 2; ++j) { b0[j][0] = BRD(cur, 0, j, 0); b0[j][1] = BRD(cur, 0, j, 1); }
        __builtin_amdgcn_sched_barrier(0);
        __builtin_amdgcn_s_barrier();
        asm volatile("s_waitcnt lgkmcnt(0)" ::: "memory");
        __builtin_amdgcn_sched_barrier(0);
        __builtin_amdgcn_s_setprio(1);
#pragma unroll
        for (int i = 0; i < 4; ++i)
#pragma unroll
            for (int j = 0; j < 2; ++j) {
                acc[i][j] = __builtin_amdgcn_mfma_f32_16x16x32_bf16(a[i][0], b0[j][0], acc[i][j], 0, 0, 0);
                acc[i][j] = __builtin_amdgcn_mfma_f32_16x16x32_bf16(a[i][1], b0[j][1], acc[i][j], 0, 0, 0);
            }
        __builtin_amdgcn_s_setprio(0);
        __builtin_amdgcn_s_barrier();

        // ======== phase 2: quadrant (0,1); reads B-QN1 (4); stage A(v+2) QM0 quarters
#pragma unroll
        for (int j = 0; j < 2; ++j) { b1[j][0] = BRD(cur, 1, j, 0); b1[j][1] = BRD(cur, 1, j, 1); }
        if (sN2) { STG_A(cur, 0, v + 2); STG_A(cur, 2, v + 2); }
        __builtin_amdgcn_sched_barrier(0);
        __builtin_amdgcn_s_barrier();
        asm volatile("s_waitcnt lgkmcnt(0)" ::: "memory");
        __builtin_amdgcn_sched_barrier(0);
        __builtin_amdgcn_s_setprio(1);
#pragma unroll
        for (int i = 0; i < 4; ++i)
#pragma unroll
            for (int j = 0; j < 2; ++j) {
                acc[i][2 + j] = __builtin_amdgcn_mfma_f32_16x16x32_bf16(a[i][0], b1[j][0], acc[i][2 + j], 0, 0, 0);
                acc[i][2 + j] = __builtin_amdgcn_mfma_f32_16x16x32_bf16(a[i][1], b1[j][1], acc[i][2 + j], 0, 0, 0);
            }
        __builtin_amdgcn_s_setprio(0);
        __builtin_amdgcn_s_barrier();

        // ======== phase 3: quadrant (1,0); reads A-QM1 (8); stage B(v+2) rows 0-127
#pragma unroll
        for (int i = 0; i < 4; ++i) { a[i][0] = ARD(cur, 1, i, 0); a[i][1] = ARD(cur, 1, i, 1); }
        if (sN2) { STG_B(cur, 0, v + 2); STG_B(cur, 1, v + 2); }
        __builtin_amdgcn_sched_barrier(0);
        __builtin_amdgcn_s_barrier();
        asm volatile("s_waitcnt lgkmcnt(0)" ::: "memory");
        __builtin_amdgcn_sched_barrier(0);
        __builtin_amdgcn_s_setprio(1);
#pragma unroll
        for (int i = 0; i < 4; ++i)
#pragma unroll
            for (int j = 0; j < 2; ++j) {
                acc[4 + i][j] = __builtin_amdgcn_mfma_f32_16x16x32_bf16(a[i][0], b0[j][0], acc[4 + i][j], 0, 0, 0);
                acc[4 + i][j] = __builtin_amdgcn_mfma_f32_16x16x32_bf16(a[i][1], b0[j][1], acc[4 + i][j], 0, 0, 0);
            }
        __builtin_amdgcn_s_setprio(0);
        __builtin_amdgcn_s_barrier();

        // ======== phase 4: quadrant (1,1); no reads; stage B(v+2) rows 128-255 + A(v+2) QM1
        if (sN2) { STG_B(cur, 2, v + 2); STG_B(cur, 3, v + 2); STG_A(cur, 1, v + 2); STG_A(cur, 3, v + 2); }
        __builtin_amdgcn_sched_barrier(0);
        __builtin_amdgcn_s_barrier();
        __builtin_amdgcn_s_setprio(1);
#pragma unroll
        for (int i = 0; i < 4; ++i)
#pragma unroll
            for (int j = 0; j < 2; ++j) {
                acc[4 + i][2 + j] = __builtin_amdgcn_mfma_f32_16x16x32_bf16(a[i][0], b1[j][0], acc[4 + i][2 + j], 0, 0, 0);
                acc[4 + i][2 + j] = __builtin_amdgcn_mfma_f32_16x16x32_bf16(a[i][1], b1[j][1], acc[4 + i][2 + j], 0, 0, 0);
            }
        __builtin_amdgcn_s_setprio(0);
        // tile boundary: guard tile v+1 (its 8 loads are the oldest outstanding);
        // tile v+2's 8 loads (issued this tile) may stay in flight.
        if (sN2) { asm volatile("s_waitcnt vmcnt(8)" ::: "memory"); }
        else     { asm volatile("s_waitcnt vmcnt(0)" ::: "memory"); }
        __builtin_amdgcn_s_barrier();
        __builtin_amdgcn_sched_barrier(0);
    }

    // ---- epilogue: tanh, weight by v, reduce this wave's 64 columns
#pragma unroll
    for (int i8 = 0; i8 < 8; ++i8) {
#pragma unroll
        for (int r = 0; r < 4; ++r) {
            float sum = fast_tanh(acc[i8][0][r]) * vv[0]
                      + fast_tanh(acc[i8][1][r]) * vv[1]
                      + fast_tanh(acc[i8][2][r]) * vv[2]
                      + fast_tanh(acc[i8][3][r]) * vv[3];
            sum += __shfl_xor(sum, 1);
            sum += __shfl_xor(sum, 2);
            sum += __shfl_xor(sum, 4);
            sum += __shfl_xor(sum, 8);
            if (fr == 0) {
                int row = m0 + wm * 128 + i8 * 16 + fq * 4 + r;
                atomicAdd(&U[(size_t)hop * M_TOT + row], sum);
            }
        }
    }
#undef STG_A
#undef STG_B
#undef ARD
#undef BRD
}

// ---------------------------------------------------------------------------
// Kernel 5: softmax over s per (b,hop).  grid 64, block 256.
// ---------------------------------------------------------------------------
__global__ void k_softmax(const float* __restrict__ U, float* __restrict__ alpha) {
    int id  = blockIdx.x;
    int hop = id >> 5, b = id & 31;
    int t = threadIdx.x;
    const float* u = U + (size_t)hop * M_TOT + (size_t)b * S_;
    float* al = alpha + (size_t)hop * M_TOT + (size_t)b * S_;
    float v[8];
    float mx = -1e30f;
#pragma unroll
    for (int i = 0; i < 8; ++i) { v[i] = u[t + i * 256]; mx = fmaxf(mx, v[i]); }
    __shared__ float red[256];
    red[t] = mx; __syncthreads();
    for (int s = 128; s > 0; s >>= 1) {
        if (t < s) red[t] = fmaxf(red[t], red[t + s]);
        __syncthreads();
    }
    mx = red[0]; __syncthreads();
    float sum = 0.f;
#pragma unroll
    for (int i = 0; i < 8; ++i) { v[i] = expf(v[i] - mx); sum += v[i]; }
    red[t] = sum; __syncthreads();
    for (int s = 128; s > 0; s >>= 1) {
        if (t < s) red[t] += red[t + s];
        __syncthreads();
    }
    float inv = 1.0f / red[0];
#pragma unroll
    for (int i = 0; i < 8; ++i) al[t + i * 256] = v[i] * inv;
}

// ---------------------------------------------------------------------------
// Kernel 6: u_att = sum_s inputs[b,s,:] * alpha[b,s]. grid (32 b, 64 sc of 32).
// ---------------------------------------------------------------------------
__global__ void k_wsum(const unsigned short* __restrict__ Xbf,
                       const float* __restrict__ alpha,
                       float* __restrict__ out1 /* pre-zeroed */,
                       float* __restrict__ out2 /* pre-zeroed */) {
    int b  = blockIdx.x;
    int sc = blockIdx.y;
    int t  = threadIdx.x;
    __shared__ float a1[32], a2[32];
    int s0 = sc * 32;
    if (t < 32)       a1[t]      = alpha[(size_t)b * S_ + s0 + t];
    else if (t < 64)  a2[t - 32] = alpha[(size_t)M_TOT + (size_t)b * S_ + s0 + (t - 32)];
    __syncthreads();
    const ushort4* xr = (const ushort4*)(Xbf + ((size_t)b * S_ + s0) * H_);
    float x0a = 0.f, x1a = 0.f, x2a = 0.f, x3a = 0.f;
    float x0b = 0.f, x1b = 0.f, x2b = 0.f, x3b = 0.f;
    for (int s = 0; s < 32; ++s) {
        ushort4 u = xr[(size_t)s * 256 + t];
        float f0 = bf2f(u.x), f1 = bf2f(u.y), f2 = bf2f(u.z), f3 = bf2f(u.w);
        float w1 = a1[s], w2 = a2[s];
        x0a += f0 * w1; x1a += f1 * w1; x2a += f2 * w1; x3a += f3 * w1;
        x0b += f0 * w2; x1b += f1 * w2; x2b += f2 * w2; x3b += f3 * w2;
    }
    float* o1 = out1 + b * H_ + t * 4;
    float* o2 = out2 + b * H_ + t * 4;
    atomicAdd(o1 + 0, x0a); atomicAdd(o1 + 1, x1a);
    atomicAdd(o1 + 2, x2a); atomicAdd(o1 + 3, x3a);
    atomicAdd(o2 + 0, x0b); atomicAdd(o2 + 1, x1b);
    atomicAdd(o2 + 2, x2b); atomicAdd(o2 + 3, x3b);
}

// ---------------------------------------------------------------------------
extern "C" void kernel_launch(void* const* d_in, const int* in_sizes, int n_in,
                              void* d_out, int out_size, void* d_ws, size_t ws_size,
                              hipStream_t stream) {
    const float* inputs = (const float*)d_in[0];
    const float* q      = (const float*)d_in[1];
    const float* W1     = (const float*)d_in[2];
    const float* Wm1    = (const float*)d_in[3];
    const float* Wh1    = (const float*)d_in[4];
    const float* W2     = (const float*)d_in[5];
    const float* Wm2    = (const float*)d_in[6];
    const float* Wh2    = (const float*)d_in[7];
    float* out = (float*)d_out;     // [3,B,H]: mean | u_att1 | u_att2

    // workspace layout (bytes); total ~133.5 MiB + 0.25 MiB
    char* ws = (char*)d_ws;
    unsigned short* Xbf  = (unsigned short*)(ws);                 // 134217728 B
    unsigned short* WT   = (unsigned short*)(ws + 134217728);     //   4194304 B
    float*          vcat = (float*)(ws + 138412032);              //    262144 B
    float*          U    = (float*)(ws + 138674176);              //    524288 B
    float*          alph = (float*)(ws + 139198464);              //    524288 B
    float*          vtmp = (float*)(ws + 139722752);              //    262144 B

    hipMemsetAsync(d_out, 0, (size_t)out_size * sizeof(float), stream);
    // zero U + alph + vtmp in one shot (contiguous region)
    hipMemsetAsync(U, 0, 524288 + 524288 + 262144, stream);

    k_meanconv<<<dim3(32, 64), 256, 0, stream>>>(inputs, Xbf, out);
    k_wconv  <<<dim3(2048),    256, 0, stream>>>(W1, W2, WT);
    k_vpart  <<<dim3(32, 2, 8), 256, 0, stream>>>(out, q, Wm1, Wm2, vtmp);
    k_vfin   <<<dim3(256),     256, 0, stream>>>(vtmp, Wh1, Wh2, vcat);
    k_gemm   <<<dim3(2048),    512, 0, stream>>>(Xbf, WT, vcat, U);
    k_softmax<<<dim3(64),      256, 0, stream>>>(U, alph);
    k_wsum   <<<dim3(32, 64),  256, 0, stream>>>(Xbf, alph, out + 32768, out + 65536);
}